// Round 18
// baseline (121.655 us; speedup 1.0000x reference)
//
#include <hip/hip_runtime.h>

#define TOKENS 16384
#define EMB 4096
#define NEXP 64
#define BK 32
#define KSP 2
#define KPER (EMB / KSP)   // 2048
#define NCH (KPER / BK)    // 64 chunks per wave

typedef __attribute__((ext_vector_type(8))) short short8;
typedef __attribute__((ext_vector_type(4))) float f32x4;
typedef __attribute__((ext_vector_type(4))) unsigned short ush4;

#define WP_USHORTS (3 * NEXP * EMB)   // 1.5 MB bf16 W-planes (L2-resident)
#define WP_FLOATS  (WP_USHORTS / 2)

// async global->LDS, 16B/lane; dest = wave-uniform base + lane*16
__device__ __forceinline__ void gl_lds16(const void* g, void* lds) {
    __builtin_amdgcn_global_load_lds(
        (const __attribute__((address_space(1))) void*)g,
        (__attribute__((address_space(3))) void*)lds, 16, 0, 0);
}

// fp32 -> 3x bf16, scalar (W prep): hi RN, mid/lo trunc (R7-R16 exact).
__device__ __forceinline__ void split3(float x, unsigned short& h,
                                       unsigned short& m, unsigned short& l) {
    unsigned u = __float_as_uint(x);
    unsigned r = u + 0x7FFFu + ((u >> 16) & 1u);
    float hF = __uint_as_float(r & 0xFFFF0000u);
    h = (unsigned short)(r >> 16);
    float r1 = x - hF;
    unsigned u1 = __float_as_uint(r1);
    float mF = __uint_as_float(u1 & 0xFFFF0000u);
    m = (unsigned short)(u1 >> 16);
    float r2 = r1 - mF;
    l = (unsigned short)(__float_as_uint(r2) >> 16);
}

// pair-wise split -> packed bf16 words (identical planes; v_perm packing).
__device__ __forceinline__ void split3_pair(float x0, float x1,
        unsigned& hw, unsigned& mw, unsigned& lw) {
    unsigned u0 = __float_as_uint(x0), u1 = __float_as_uint(x1);
    unsigned r0 = u0 + 0x7FFFu + ((u0 >> 16) & 1u);
    unsigned r1 = u1 + 0x7FFFu + ((u1 >> 16) & 1u);
    hw = __builtin_amdgcn_perm(r1, r0, 0x07060302u);
    float s0 = x0 - __uint_as_float(r0 & 0xFFFF0000u);
    float s1 = x1 - __uint_as_float(r1 & 0xFFFF0000u);
    unsigned v0 = __float_as_uint(s0), v1 = __float_as_uint(s1);
    mw = __builtin_amdgcn_perm(v1, v0, 0x07060302u);
    float t0 = s0 - __uint_as_float(v0 & 0xFFFF0000u);
    float t1 = s1 - __uint_as_float(v1 & 0xFFFF0000u);
    lw = __builtin_amdgcn_perm(__float_as_uint(t1), __float_as_uint(t0), 0x07060302u);
}

// 8 floats (one lane's 32-k A slice) -> three short8 MFMA fragments
__device__ __forceinline__ void build_frags(const float4& a0, const float4& a1,
        short8& H, short8& M, short8& L) {
    union { short8 v; unsigned u[4]; } h_, m_, l_;
    split3_pair(a0.x, a0.y, h_.u[0], m_.u[0], l_.u[0]);
    split3_pair(a0.z, a0.w, h_.u[1], m_.u[1], l_.u[1]);
    split3_pair(a1.x, a1.y, h_.u[2], m_.u[2], l_.u[2]);
    split3_pair(a1.z, a1.w, h_.u[3], m_.u[3], l_.u[3]);
    H = h_.v; M = m_.v; L = l_.v;
}

// prep: split W into 3 bf16 planes Wp[plane][e][k] (flat row r = plane*64+e)
__global__ __launch_bounds__(256) void split_w(const float* __restrict__ W,
                                               unsigned short* __restrict__ Wp) {
    const int i = (blockIdx.x * 256 + threadIdx.x) * 4;
    const float4 v = *reinterpret_cast<const float4*>(W + i);
    ush4 h, m, l;
#pragma unroll
    for (int e = 0; e < 4; ++e) {
        unsigned short he, me, le;
        split3(reinterpret_cast<const float*>(&v)[e], he, me, le);
        h[e] = he; m[e] = me; l[e] = le;
    }
    *reinterpret_cast<ush4*>(Wp + i) = h;
    *reinterpret_cast<ush4*>(Wp + NEXP * EMB + i) = m;
    *reinterpret_cast<ush4*>(Wp + 2 * NEXP * EMB + i) = l;
}

// Fused router, R18 = R17 (barrier-free wave-private K-loop) + VMEM
// ISSUE-ORDER FENCES. R17's absmax-52 failure: ISSUE_B (6 gl_lds) and
// ISSUE_A (4 loads) shared one scheduling region, so the compiler could
// interleave them; with mixed issue order, vmcnt(4) no longer retires
// exactly {A(c), st(c)} and the MFMA could read a buffer whose stage ops
// were still in flight (stale B -> flipped top-2). Fix: sched_barrier(0)
// AFTER the B-stage group and AFTER the A-load group, pinning the queue
// to [A(c+1), st(c+1), A(c+2)] at every iter entry (counted-vmcnt is only
// sound with order-pinned VMEM groups - T4's hidden prerequisite, and the
// fence R14 had that R17 dropped).
// Structure: wave = 32 tok x 32 exp; 8 waves = (h, e2, g); each wave
// stages its OWN B (6 KB/buf x2) and reads only its own buffers -> no
// s_barrier in the loop; waves self-pace on counted vmcnt; 2 waves/SIMD
// cover each other's stalls. Numerics: split-3/6-term/segregated-acc
// (R7-R16 exact); KSP=2 -> 64-long fp32 MFMA chains, err ~2e-7 << gap.
#define ISSUE_B(C, BUF)                                                         \
    _Pragma("unroll")                                                           \
    for (int q = 0; q < 6; ++q)                                                 \
        gl_lds16(gbw[q] + (C) * BK, &sBw[BUF][16 * q][0]);

#define ISSUE_A(C, ASET)                                                        \
    _Pragma("unroll")                                                           \
    for (int ti = 0; ti < 2; ++ti) {                                            \
        ASET[ti][0] = *reinterpret_cast<const float4*>(ax[ti] + (C) * BK);      \
        ASET[ti][1] = *reinterpret_cast<const float4*>(ax[ti] + (C) * BK + 4);  \
    }

#define MFMA_BLOCK(BUFC, AH0, AM0, AL0, AH1, AM1, AL1)                          \
    _Pragma("unroll")                                                           \
    for (int et = 0; et < 2; ++et) {                                            \
        const unsigned short* bp = &sBw[BUFC][et * 16 + lr][lo * 8];            \
        const short8 bH = *reinterpret_cast<const short8*>(bp);                 \
        const short8 bM = *reinterpret_cast<const short8*>(bp + 32 * BK);       \
        const short8 bL = *reinterpret_cast<const short8*>(bp + 64 * BK);       \
        accH[0][et] = __builtin_amdgcn_mfma_f32_16x16x32_bf16(AH0, bH, accH[0][et], 0, 0, 0); \
        accL[0][et] = __builtin_amdgcn_mfma_f32_16x16x32_bf16(AH0, bM, accL[0][et], 0, 0, 0); \
        accL[0][et] = __builtin_amdgcn_mfma_f32_16x16x32_bf16(AM0, bH, accL[0][et], 0, 0, 0); \
        accL[0][et] = __builtin_amdgcn_mfma_f32_16x16x32_bf16(AM0, bM, accL[0][et], 0, 0, 0); \
        accL[0][et] = __builtin_amdgcn_mfma_f32_16x16x32_bf16(AH0, bL, accL[0][et], 0, 0, 0); \
        accL[0][et] = __builtin_amdgcn_mfma_f32_16x16x32_bf16(AL0, bH, accL[0][et], 0, 0, 0); \
        accH[1][et] = __builtin_amdgcn_mfma_f32_16x16x32_bf16(AH1, bH, accH[1][et], 0, 0, 0); \
        accL[1][et] = __builtin_amdgcn_mfma_f32_16x16x32_bf16(AH1, bM, accL[1][et], 0, 0, 0); \
        accL[1][et] = __builtin_amdgcn_mfma_f32_16x16x32_bf16(AM1, bH, accL[1][et], 0, 0, 0); \
        accL[1][et] = __builtin_amdgcn_mfma_f32_16x16x32_bf16(AM1, bM, accL[1][et], 0, 0, 0); \
        accL[1][et] = __builtin_amdgcn_mfma_f32_16x16x32_bf16(AH1, bL, accL[1][et], 0, 0, 0); \
        accL[1][et] = __builtin_amdgcn_mfma_f32_16x16x32_bf16(AL1, bH, accL[1][et], 0, 0, 0); \
    }

#define ITER(C, ASET, BUFC, VM, DO_B, DO_A) do {                                \
    asm volatile("s_waitcnt vmcnt(" #VM ")" ::: "memory");                      \
    __builtin_amdgcn_sched_barrier(0);                                          \
    if (DO_B) { ISSUE_B((C) + 1, (BUFC) ^ 1); }                                 \
    __builtin_amdgcn_sched_barrier(0);  /* pin: B-stage ops issue first */      \
    short8 aH0, aM0, aL0, aH1, aM1, aL1;                                        \
    build_frags(ASET[0][0], ASET[0][1], aH0, aM0, aL0);                         \
    build_frags(ASET[1][0], ASET[1][1], aH1, aM1, aL1);                         \
    if (DO_A) { ISSUE_A((C) + 2, ASET); }                                       \
    __builtin_amdgcn_sched_barrier(0);  /* pin: A-loads before MFMA cluster */  \
    MFMA_BLOCK(BUFC, aH0, aM0, aL0, aH1, aM1, aL1)                              \
} while (0)

__global__ __launch_bounds__(512) void router_fused(
    const float* __restrict__ x, const unsigned short* __restrict__ Wp,
    const float* __restrict__ b, float* __restrict__ out)
{
    __shared__ unsigned short sB[8][2][96][BK];   // 96 KB, wave-private slices

    const int t  = threadIdx.x;
    const int w  = t >> 6;     // wave 0..7
    const int l  = t & 63;
    const int h  = w & 1;           // token half
    const int e2 = (w >> 1) & 1;    // expert half
    const int g  = w >> 2;          // k-split 0..1
    const int lr = l & 15;          // A token-row / B expert-col
    const int lo = l >> 4;          // k-octet selector
    const int tokB = blockIdx.x * 64;
    const int tok0 = tokB + h * 32;
    const int eb   = e2 * 32;
    const int kb   = g * KPER;

    unsigned short (*sBw)[96][BK] = sB[w];   // private buffers

    const float* ax[2];
    ax[0] = x + (size_t)(tok0 + lr) * EMB + kb + lo * 8;
    ax[1] = ax[0] + (size_t)16 * EMB;

    // private B staging: instr q (plane q>>1, rowhalf q&1): LDS rows
    // 16q..16q+15; lane l -> row 16q+(l>>2), 16B piece l&3.
    const unsigned short* gbw[6];
#pragma unroll
    for (int q = 0; q < 6; ++q)
        gbw[q] = Wp + (size_t)((q >> 1) * 64 + eb + (q & 1) * 16 + (l >> 2)) * EMB
               + kb + 8 * (l & 3);

    f32x4 accH[2][2], accL[2][2];
#pragma unroll
    for (int ti = 0; ti < 2; ++ti)
#pragma unroll
        for (int et = 0; et < 2; ++et) {
            accH[ti][et] = (f32x4){0.f, 0.f, 0.f, 0.f};
            accL[ti][et] = (f32x4){0.f, 0.f, 0.f, 0.f};
        }

    // prologue FIFO (order-pinned): st(0)6, A(0)4, A(1)4
    float4 aA[2][2], aB[2][2];
    ISSUE_B(0, 0);
    __builtin_amdgcn_sched_barrier(0);
    ISSUE_A(0, aA);
    __builtin_amdgcn_sched_barrier(0);
    ISSUE_A(1, aB);
    __builtin_amdgcn_sched_barrier(0);

#pragma unroll 1
    for (int cc = 0; cc < NCH - 2; cc += 2) {   // iters 0..61
        ITER(cc,     aA, 0, 4, true, true);
        ITER(cc + 1, aB, 1, 4, true, true);
    }
    ITER(NCH - 2, aA, 0, 4, true,  false);      // stage 63, no A(64)
    ITER(NCH - 1, aB, 1, 0, false, false);      // full drain

    // ---- fused epilogue (R14 pattern, KSP=2) ----
    __syncthreads();   // first and only cross-wave sync
    float* logits = reinterpret_cast<float*>(&sB[0][0][0][0]); // [2][64][65]
#pragma unroll
    for (int ti = 0; ti < 2; ++ti)
#pragma unroll
        for (int et = 0; et < 2; ++et)
#pragma unroll
            for (int j = 0; j < 4; ++j) {
                const int ltok = h * 32 + ti * 16 + lo * 4 + j;
                logits[(g * 64 + ltok) * 65 + eb + et * 16 + lr]
                    = accH[ti][et][j] + accL[ti][et][j];
            }
    __syncthreads();

    double* sv = reinterpret_cast<double*>(logits + KSP * 64 * 65); // [64][8][2]
    int*    si = reinterpret_cast<int*>(sv + 64 * 8 * 2);

    const int tok  = t >> 3;    // 0..63
    const int part = t & 7;     // 8 experts each
    double v[8];
#pragma unroll
    for (int j = 0; j < 8; ++j) v[j] = 0.0;
#pragma unroll
    for (int gg = 0; gg < KSP; ++gg)
#pragma unroll
        for (int j = 0; j < 8; ++j)
            v[j] += (double)logits[(gg * 64 + tok) * 65 + part * 8 + j];
#pragma unroll
    for (int j = 0; j < 8; ++j) v[j] += (double)b[part * 8 + j];

    double v1 = -1e300, v2 = -1e300; int i1 = 0, i2 = 0;
#pragma unroll
    for (int j = 0; j < 8; ++j) {        // ascending: ties keep lowest idx
        const int e = part * 8 + j;
        if (v[j] > v1)      { v2 = v1; i2 = i1; v1 = v[j]; i1 = e; }
        else if (v[j] > v2) { v2 = v[j]; i2 = e; }
    }
    sv[(tok * 8 + part) * 2 + 0] = v1;
    sv[(tok * 8 + part) * 2 + 1] = v2;
    si[(tok * 8 + part) * 2 + 0] = i1;
    si[(tok * 8 + part) * 2 + 1] = i2;
    __syncthreads();

    if (part == 0) {
        double m1 = -1e300, m2 = -1e300; int j1 = 0, j2 = 0;
#pragma unroll
        for (int p = 0; p < 8; ++p)      // ascending parts: lowest idx on tie
#pragma unroll
            for (int r = 0; r < 2; ++r) {
                const double vv = sv[(tok * 8 + p) * 2 + r];
                const int    ii = si[(tok * 8 + p) * 2 + r];
                if (vv > m1)      { m2 = m1; j2 = j1; m1 = vv; j1 = ii; }
                else if (vv > m2) { m2 = vv; j2 = ii; }
            }
        const float e2s = expf((float)(m2 - m1));   // <= 1
        const float inv = 1.0f / (1.0f + e2s);
        const int gt = tokB + tok;
        out[2 * gt]     = (float)j1;
        out[2 * gt + 1] = (float)j2;
        out[2 * TOKENS + 2 * gt]     = inv;
        out[2 * TOKENS + 2 * gt + 1] = e2s * inv;
    }
}

extern "C" void kernel_launch(void* const* d_in, const int* in_sizes, int n_in,
                              void* d_out, int out_size, void* d_ws, size_t ws_size,
                              hipStream_t stream) {
    const float* x = (const float*)d_in[0];
    const float* W = (const float*)d_in[1];
    const float* b = (const float*)d_in[2];
    float* out = (float*)d_out;
    unsigned short* Wp = (unsigned short*)d_ws;   // 1.5 MB, always fits

    split_w<<<dim3(NEXP * EMB / 1024), dim3(256), 0, stream>>>(W, Wp);
    router_fused<<<dim3(TOKENS / 64), dim3(512), 0, stream>>>(x, Wp, b, out);
}

// Round 19
// 102.135 us; speedup vs baseline: 1.1911x; 1.1911x over previous
//
#include <hip/hip_runtime.h>

#define TOKENS 16384
#define EMB 4096
#define NEXP 64
#define BK 32
#define KSP 2
#define KPER (EMB / KSP)   // 2048
#define NCH (KPER / BK)    // 64

typedef __attribute__((ext_vector_type(8))) short short8;
typedef __attribute__((ext_vector_type(4))) float f32x4;
typedef __attribute__((ext_vector_type(4))) unsigned short ush4;

#define WP_USHORTS (3 * NEXP * EMB)   // 1.5 MB bf16 W-planes (L2-resident)
#define WP_FLOATS  (WP_USHORTS / 2)

// async global->LDS, 16B/lane; dest = wave-uniform base + lane*16
__device__ __forceinline__ void gl_lds16(const void* g, void* lds) {
    __builtin_amdgcn_global_load_lds(
        (const __attribute__((address_space(1))) void*)g,
        (__attribute__((address_space(3))) void*)lds, 16, 0, 0);
}

// fp32 -> 3x bf16, scalar (W prep): hi RN, mid/lo trunc (R7-R18 exact).
__device__ __forceinline__ void split3(float x, unsigned short& h,
                                       unsigned short& m, unsigned short& l) {
    unsigned u = __float_as_uint(x);
    unsigned r = u + 0x7FFFu + ((u >> 16) & 1u);
    float hF = __uint_as_float(r & 0xFFFF0000u);
    h = (unsigned short)(r >> 16);
    float r1 = x - hF;
    unsigned u1 = __float_as_uint(r1);
    float mF = __uint_as_float(u1 & 0xFFFF0000u);
    m = (unsigned short)(u1 >> 16);
    float r2 = r1 - mF;
    l = (unsigned short)(__float_as_uint(r2) >> 16);
}

// pair-wise split -> packed bf16 words (identical planes; v_perm packing).
__device__ __forceinline__ void split3_pair(float x0, float x1,
        unsigned& hw, unsigned& mw, unsigned& lw) {
    unsigned u0 = __float_as_uint(x0), u1 = __float_as_uint(x1);
    unsigned r0 = u0 + 0x7FFFu + ((u0 >> 16) & 1u);
    unsigned r1 = u1 + 0x7FFFu + ((u1 >> 16) & 1u);
    hw = __builtin_amdgcn_perm(r1, r0, 0x07060302u);
    float s0 = x0 - __uint_as_float(r0 & 0xFFFF0000u);
    float s1 = x1 - __uint_as_float(r1 & 0xFFFF0000u);
    unsigned v0 = __float_as_uint(s0), v1 = __float_as_uint(s1);
    mw = __builtin_amdgcn_perm(v1, v0, 0x07060302u);
    float t0 = s0 - __uint_as_float(v0 & 0xFFFF0000u);
    float t1 = s1 - __uint_as_float(v1 & 0xFFFF0000u);
    lw = __builtin_amdgcn_perm(__float_as_uint(t1), __float_as_uint(t0), 0x07060302u);
}

// 8 floats (one lane's 32-k A slice) -> three short8 MFMA fragments
__device__ __forceinline__ void build_frags(const float4& a0, const float4& a1,
        short8& H, short8& M, short8& L) {
    union { short8 v; unsigned u[4]; } h_, m_, l_;
    split3_pair(a0.x, a0.y, h_.u[0], m_.u[0], l_.u[0]);
    split3_pair(a0.z, a0.w, h_.u[1], m_.u[1], l_.u[1]);
    split3_pair(a1.x, a1.y, h_.u[2], m_.u[2], l_.u[2]);
    split3_pair(a1.z, a1.w, h_.u[3], m_.u[3], l_.u[3]);
    H = h_.v; M = m_.v; L = l_.v;
}

// prep: split W into 3 bf16 planes Wp[plane][e][k] (flat row r = plane*64+e)
__global__ __launch_bounds__(256) void split_w(const float* __restrict__ W,
                                               unsigned short* __restrict__ Wp) {
    const int i = (blockIdx.x * 256 + threadIdx.x) * 4;
    const float4 v = *reinterpret_cast<const float4*>(W + i);
    ush4 h, m, l;
#pragma unroll
    for (int e = 0; e < 4; ++e) {
        unsigned short he, me, le;
        split3(reinterpret_cast<const float*>(&v)[e], he, me, le);
        h[e] = he; m[e] = me; l[e] = le;
    }
    *reinterpret_cast<ush4*>(Wp + i) = h;
    *reinterpret_cast<ush4*>(Wp + NEXP * EMB + i) = m;
    *reinterpret_cast<ush4*>(Wp + 2 * NEXP * EMB + i) = l;
}

// Fused router, R19 = R14 halved: 2 independent barrier groups per CU.
// R18 proved barrier-free/wave-private is worse (121us); R14 (76us) has the
// right structure (shared-B, counted vmcnt, block barriers) but runs 1
// block/CU -> all 8 waves stall together at each barrier with nothing to
// cover. Here: 256 thr = 4 waves = (g ksplit x h tokhalf), wave = 16 tok x
// 64 exp, block = 32 tokens, KSP=2 (NCH=64), LDS = 2x2x12 KB = 48 KB ->
// grid 512 = 2 blocks/CU. Same proven per-iter schedule; barriers sync 4
// waves, and the co-resident block's waves cover the drain.
// FIFO (re-derived for 16-tok wave): queue entering iter c =
// [A(c)2, st(c)6, A(c+1)2] -> vmcnt(2) retires A(c)+st(c); tails
// vmcnt(2)/vmcnt(0). VMEM groups order-pinned (R17/R18 lesson).
// Numerics: split-3/6-term/segregated-acc; KSP=2 combine in fp64
// (R18-validated: absmax 0.0039, idx exact).
#define MFMA_BLOCK(BUFC, AH0, AM0, AL0)                                         \
    _Pragma("unroll")                                                           \
    for (int et = 0; et < 4; ++et) {                                            \
        const unsigned short* bp = &sB[g][BUFC][et * 16 + lr][lo * 8];          \
        const short8 bH = *reinterpret_cast<const short8*>(bp);                 \
        const short8 bM = *reinterpret_cast<const short8*>(bp + 64 * BK);       \
        const short8 bL = *reinterpret_cast<const short8*>(bp + 128 * BK);      \
        accH[et] = __builtin_amdgcn_mfma_f32_16x16x32_bf16(AH0, bH, accH[et], 0, 0, 0); \
        accL[et] = __builtin_amdgcn_mfma_f32_16x16x32_bf16(AH0, bM, accL[et], 0, 0, 0); \
        accL[et] = __builtin_amdgcn_mfma_f32_16x16x32_bf16(AM0, bH, accL[et], 0, 0, 0); \
        accL[et] = __builtin_amdgcn_mfma_f32_16x16x32_bf16(AM0, bM, accL[et], 0, 0, 0); \
        accL[et] = __builtin_amdgcn_mfma_f32_16x16x32_bf16(AH0, bL, accL[et], 0, 0, 0); \
        accL[et] = __builtin_amdgcn_mfma_f32_16x16x32_bf16(AL0, bH, accL[et], 0, 0, 0); \
    }

#define ISSUE_B(C, BUF)                                                         \
    _Pragma("unroll")                                                           \
    for (int p = 0; p < 6; ++p)                                                 \
        gl_lds16(gb[p] + (C) * BK, &sB[g][BUF][16 * (6 * h + p)][0]);

#define ISSUE_A(C, ASET) do {                                                   \
    ASET[0] = *reinterpret_cast<const float4*>(ax + (C) * BK);                  \
    ASET[1] = *reinterpret_cast<const float4*>(ax + (C) * BK + 4);              \
} while (0)

#define ITER(C, ASET, BUFC, VM, DO_B, DO_A) do {                                \
    asm volatile("s_waitcnt vmcnt(" #VM ")" ::: "memory");                      \
    __builtin_amdgcn_s_barrier();                                               \
    if (DO_B) { ISSUE_B((C) + 1, (BUFC) ^ 1); }                                 \
    __builtin_amdgcn_sched_barrier(0);  /* pin B-stage group */                 \
    short8 aH0, aM0, aL0;                                                       \
    build_frags(ASET[0], ASET[1], aH0, aM0, aL0);                               \
    if (DO_A) { ISSUE_A((C) + 2, ASET); }                                       \
    __builtin_amdgcn_sched_barrier(0);  /* pin A-load group */                  \
    MFMA_BLOCK(BUFC, aH0, aM0, aL0)                                             \
} while (0)

__global__ __launch_bounds__(256, 2) void router_fused(
    const float* __restrict__ x, const unsigned short* __restrict__ Wp,
    const float* __restrict__ b, float* __restrict__ out)
{
    __shared__ unsigned short sB[KSP][2][192][BK];   // 48 KB -> 2 blocks/CU

    const int t  = threadIdx.x;
    const int w  = t >> 6;     // wave 0..3
    const int l  = t & 63;
    const int g  = w >> 1;     // k-split group 0..1
    const int h  = w & 1;      // token half 0/1
    const int lr = l & 15;     // A token-row / B expert-col
    const int lo = l >> 4;     // k-octet selector
    const int tokB = blockIdx.x * 32;
    const int tok0 = tokB + h * 16;
    const int kb   = g * KPER;

    const float* ax = x + (size_t)(tok0 + lr) * EMB + kb + lo * 8;

    // B staging: wave (g,h), p=0..5 (q=6h+p): sB[g] rows 16q..16q+15;
    // lane l -> row 16q+(l>>2), 16B piece l&3.
    const unsigned short* gb[6];
#pragma unroll
    for (int p = 0; p < 6; ++p)
        gb[p] = Wp + (size_t)(16 * (6 * h + p) + (l >> 2)) * EMB + kb + 8 * (l & 3);

    f32x4 accH[4], accL[4];
#pragma unroll
    for (int et = 0; et < 4; ++et) {
        accH[et] = (f32x4){0.f, 0.f, 0.f, 0.f};
        accL[et] = (f32x4){0.f, 0.f, 0.f, 0.f};
    }

    // prologue FIFO (order-pinned): st(0)6, A(0)2, A(1)2
    float4 aA[2], aB[2];
    ISSUE_B(0, 0);
    __builtin_amdgcn_sched_barrier(0);
    ISSUE_A(0, aA);
    __builtin_amdgcn_sched_barrier(0);
    ISSUE_A(1, aB);
    __builtin_amdgcn_sched_barrier(0);

#pragma unroll 1
    for (int cc = 0; cc < NCH - 2; cc += 2) {   // iters 0..61
        ITER(cc,     aA, 0, 2, true, true);
        ITER(cc + 1, aB, 1, 2, true, true);
    }
    ITER(NCH - 2, aA, 0, 2, true,  false);      // stage 63, no A(64)
    ITER(NCH - 1, aB, 1, 0, false, false);      // full drain

    // ---- fused epilogue (R14 pattern, 32 tokens, KSP=2) ----
    __syncthreads();
    float* logits = reinterpret_cast<float*>(&sB[0][0][0][0]); // [2][32][65]
#pragma unroll
    for (int et = 0; et < 4; ++et)
#pragma unroll
        for (int j = 0; j < 4; ++j) {
            const int ltok = h * 16 + lo * 4 + j;
            logits[(g * 32 + ltok) * 65 + et * 16 + lr]
                = accH[et][j] + accL[et][j];
        }
    __syncthreads();

    double* sv = reinterpret_cast<double*>(logits + KSP * 32 * 65); // [32][8][2]
    int*    si = reinterpret_cast<int*>(sv + 32 * 8 * 2);

    const int tok  = t >> 3;    // 0..31
    const int part = t & 7;     // 8 experts each
    double v[8];
#pragma unroll
    for (int j = 0; j < 8; ++j) v[j] = 0.0;
#pragma unroll
    for (int gg = 0; gg < KSP; ++gg)
#pragma unroll
        for (int j = 0; j < 8; ++j)
            v[j] += (double)logits[(gg * 32 + tok) * 65 + part * 8 + j];
#pragma unroll
    for (int j = 0; j < 8; ++j) v[j] += (double)b[part * 8 + j];

    double v1 = -1e300, v2 = -1e300; int i1 = 0, i2 = 0;
#pragma unroll
    for (int j = 0; j < 8; ++j) {        // ascending: ties keep lowest idx
        const int e = part * 8 + j;
        if (v[j] > v1)      { v2 = v1; i2 = i1; v1 = v[j]; i1 = e; }
        else if (v[j] > v2) { v2 = v[j]; i2 = e; }
    }
    sv[(tok * 8 + part) * 2 + 0] = v1;
    sv[(tok * 8 + part) * 2 + 1] = v2;
    si[(tok * 8 + part) * 2 + 0] = i1;
    si[(tok * 8 + part) * 2 + 1] = i2;
    __syncthreads();

    if (part == 0) {
        double m1 = -1e300, m2 = -1e300; int j1 = 0, j2 = 0;
#pragma unroll
        for (int p = 0; p < 8; ++p)      // ascending parts: lowest idx on tie
#pragma unroll
            for (int r = 0; r < 2; ++r) {
                const double vv = sv[(tok * 8 + p) * 2 + r];
                const int    ii = si[(tok * 8 + p) * 2 + r];
                if (vv > m1)      { m2 = m1; j2 = j1; m1 = vv; j1 = ii; }
                else if (vv > m2) { m2 = vv; j2 = ii; }
            }
        const float e2s = expf((float)(m2 - m1));   // <= 1
        const float inv = 1.0f / (1.0f + e2s);
        const int gt = tokB + tok;
        out[2 * gt]     = (float)j1;
        out[2 * gt + 1] = (float)j2;
        out[2 * TOKENS + 2 * gt]     = inv;
        out[2 * TOKENS + 2 * gt + 1] = e2s * inv;
    }
}

extern "C" void kernel_launch(void* const* d_in, const int* in_sizes, int n_in,
                              void* d_out, int out_size, void* d_ws, size_t ws_size,
                              hipStream_t stream) {
    const float* x = (const float*)d_in[0];
    const float* W = (const float*)d_in[1];
    const float* b = (const float*)d_in[2];
    float* out = (float*)d_out;
    unsigned short* Wp = (unsigned short*)d_ws;   // 1.5 MB, always fits

    split_w<<<dim3(NEXP * EMB / 1024), dim3(256), 0, stream>>>(W, Wp);
    router_fused<<<dim3(TOKENS / 32), dim3(256), 0, stream>>>(x, Wp, b, out);
}

// Round 20
// 76.814 us; speedup vs baseline: 1.5838x; 1.3296x over previous
//
#include <hip/hip_runtime.h>

#define TOKENS 16384
#define EMB 4096
#define NEXP 64
#define BK 32
#define KSP 4                 // in-block k-splits
#define KPER (EMB / KSP)      // 1024
#define NCH (KPER / BK)       // 32

typedef __attribute__((ext_vector_type(8))) short short8;
typedef __attribute__((ext_vector_type(4))) float f32x4;
typedef __attribute__((ext_vector_type(4))) unsigned short ush4;

#define WP_USHORTS (3 * NEXP * EMB)   // 1.5 MB bf16 W-planes (L2-resident)
#define WP_FLOATS  (WP_USHORTS / 2)

// async global->LDS, 16B/lane; dest = wave-uniform base + lane*16
__device__ __forceinline__ void gl_lds16(const void* g, void* lds) {
    __builtin_amdgcn_global_load_lds(
        (const __attribute__((address_space(1))) void*)g,
        (__attribute__((address_space(3))) void*)lds, 16, 0, 0);
}

// fp32 -> 3x bf16, scalar (W prep): hi RN, mid/lo trunc (R7-R14 exact).
__device__ __forceinline__ void split3(float x, unsigned short& h,
                                       unsigned short& m, unsigned short& l) {
    unsigned u = __float_as_uint(x);
    unsigned r = u + 0x7FFFu + ((u >> 16) & 1u);
    float hF = __uint_as_float(r & 0xFFFF0000u);
    h = (unsigned short)(r >> 16);
    float r1 = x - hF;
    unsigned u1 = __float_as_uint(r1);
    float mF = __uint_as_float(u1 & 0xFFFF0000u);
    m = (unsigned short)(u1 >> 16);
    float r2 = r1 - mF;
    l = (unsigned short)(__float_as_uint(r2) >> 16);
}

// pair-wise split -> packed bf16 words (identical planes; v_perm packing).
__device__ __forceinline__ void split3_pair(float x0, float x1,
        unsigned& hw, unsigned& mw, unsigned& lw) {
    unsigned u0 = __float_as_uint(x0), u1 = __float_as_uint(x1);
    unsigned r0 = u0 + 0x7FFFu + ((u0 >> 16) & 1u);
    unsigned r1 = u1 + 0x7FFFu + ((u1 >> 16) & 1u);
    hw = __builtin_amdgcn_perm(r1, r0, 0x07060302u);
    float s0 = x0 - __uint_as_float(r0 & 0xFFFF0000u);
    float s1 = x1 - __uint_as_float(r1 & 0xFFFF0000u);
    unsigned v0 = __float_as_uint(s0), v1 = __float_as_uint(s1);
    mw = __builtin_amdgcn_perm(v1, v0, 0x07060302u);
    float t0 = s0 - __uint_as_float(v0 & 0xFFFF0000u);
    float t1 = s1 - __uint_as_float(v1 & 0xFFFF0000u);
    lw = __builtin_amdgcn_perm(__float_as_uint(t1), __float_as_uint(t0), 0x07060302u);
}

// 8 floats (one lane's 32-k A slice) -> three short8 MFMA fragments
__device__ __forceinline__ void build_frags(const float4& a0, const float4& a1,
        short8& H, short8& M, short8& L) {
    union { short8 v; unsigned u[4]; } h_, m_, l_;
    split3_pair(a0.x, a0.y, h_.u[0], m_.u[0], l_.u[0]);
    split3_pair(a0.z, a0.w, h_.u[1], m_.u[1], l_.u[1]);
    split3_pair(a1.x, a1.y, h_.u[2], m_.u[2], l_.u[2]);
    split3_pair(a1.z, a1.w, h_.u[3], m_.u[3], l_.u[3]);
    H = h_.v; M = m_.v; L = l_.v;
}

// prep: split W into 3 bf16 planes Wp[plane][e][k] (flat row r = plane*64+e)
__global__ __launch_bounds__(256) void split_w(const float* __restrict__ W,
                                               unsigned short* __restrict__ Wp) {
    const int i = (blockIdx.x * 256 + threadIdx.x) * 4;
    const float4 v = *reinterpret_cast<const float4*>(W + i);
    ush4 h, m, l;
#pragma unroll
    for (int e = 0; e < 4; ++e) {
        unsigned short he, me, le;
        split3(reinterpret_cast<const float*>(&v)[e], he, me, le);
        h[e] = he; m[e] = me; l[e] = le;
    }
    *reinterpret_cast<ush4*>(Wp + i) = h;
    *reinterpret_cast<ush4*>(Wp + NEXP * EMB + i) = m;
    *reinterpret_cast<ush4*>(Wp + 2 * NEXP * EMB + i) = l;
}

// Fully fused: GEMM (split-3 bf16 MFMA) + in-block K-split combine + top-2
// + softmax -> out. BEST VERIFIED KERNEL (R14: 76.1 us, absmax 0.0).
// Block = 512 thr = 8 waves; wave (g=w>>1, h=w&1): k-split g (KPER=1024),
// tokens h*32..h*32+31 (wave = 32 tok x 64 exp -> B reads shared by 2
// A-tiles). LDS 96 KB: sB[4 groups][2 bufs][192][32] -> 1 block/CU.
// K-loop: counted vmcnt(4) (queue entering wait = [A(ks)4, st(ks)6,
// A(ks+1)4]; retires exactly A(ks)+st(ks)), raw s_barrier, 2 named A reg
// sets (copy-free), BK=32 (bank spread at b128 floor). Epilogue: fp32
// accH+accL -> LDS logits[4][64][65], fp64 4-way combine + bias, 8-part
// top-2 merge (ascending, strict > => lowest index on ties = lax.top_k),
// softmax, direct out write. Precision: split-3 bf16 (hi RN, m/l trunc),
// 6 MFMA terms, hh segregated in accH -> exact idx (absmax 0.0).
#define MFMA_BLOCK(BUFC, AH0, AM0, AL0, AH1, AM1, AL1)                          \
    _Pragma("unroll")                                                           \
    for (int et = 0; et < 4; ++et) {                                            \
        const unsigned short* bp = &sB[g][BUFC][et * 16 + lr][lo * 8];          \
        const short8 bH = *reinterpret_cast<const short8*>(bp);                 \
        const short8 bM = *reinterpret_cast<const short8*>(bp + 64 * BK);       \
        const short8 bL = *reinterpret_cast<const short8*>(bp + 128 * BK);      \
        accH[0][et] = __builtin_amdgcn_mfma_f32_16x16x32_bf16(AH0, bH, accH[0][et], 0, 0, 0); \
        accL[0][et] = __builtin_amdgcn_mfma_f32_16x16x32_bf16(AH0, bM, accL[0][et], 0, 0, 0); \
        accL[0][et] = __builtin_amdgcn_mfma_f32_16x16x32_bf16(AM0, bH, accL[0][et], 0, 0, 0); \
        accL[0][et] = __builtin_amdgcn_mfma_f32_16x16x32_bf16(AM0, bM, accL[0][et], 0, 0, 0); \
        accL[0][et] = __builtin_amdgcn_mfma_f32_16x16x32_bf16(AH0, bL, accL[0][et], 0, 0, 0); \
        accL[0][et] = __builtin_amdgcn_mfma_f32_16x16x32_bf16(AL0, bH, accL[0][et], 0, 0, 0); \
        accH[1][et] = __builtin_amdgcn_mfma_f32_16x16x32_bf16(AH1, bH, accH[1][et], 0, 0, 0); \
        accL[1][et] = __builtin_amdgcn_mfma_f32_16x16x32_bf16(AH1, bM, accL[1][et], 0, 0, 0); \
        accL[1][et] = __builtin_amdgcn_mfma_f32_16x16x32_bf16(AM1, bH, accL[1][et], 0, 0, 0); \
        accL[1][et] = __builtin_amdgcn_mfma_f32_16x16x32_bf16(AM1, bM, accL[1][et], 0, 0, 0); \
        accL[1][et] = __builtin_amdgcn_mfma_f32_16x16x32_bf16(AH1, bL, accL[1][et], 0, 0, 0); \
        accL[1][et] = __builtin_amdgcn_mfma_f32_16x16x32_bf16(AL1, bH, accL[1][et], 0, 0, 0); \
    }

#define BODY(KS, AC, BUFC) do {                                                 \
    asm volatile("s_waitcnt vmcnt(4)" ::: "memory");                            \
    __builtin_amdgcn_s_barrier();                                               \
    _Pragma("unroll")                                                           \
    for (int p = 0; p < 6; ++p)                                                 \
        gl_lds16(gb[p] + ((KS) + 1) * BK,                                       \
                 &sB[g][(BUFC) ^ 1][16 * (6 * h + p)][0]);                      \
    __builtin_amdgcn_sched_barrier(0);                                          \
    short8 aH0, aM0, aL0, aH1, aM1, aL1;                                        \
    build_frags(AC[0][0], AC[0][1], aH0, aM0, aL0);                             \
    build_frags(AC[1][0], AC[1][1], aH1, aM1, aL1);                             \
    _Pragma("unroll")                                                           \
    for (int ti = 0; ti < 2; ++ti) {                                            \
        AC[ti][0] = *reinterpret_cast<const float4*>(ax[ti] + ((KS) + 2) * BK);     \
        AC[ti][1] = *reinterpret_cast<const float4*>(ax[ti] + ((KS) + 2) * BK + 4); \
    }                                                                           \
    __builtin_amdgcn_sched_barrier(0);                                          \
    MFMA_BLOCK(BUFC, aH0, aM0, aL0, aH1, aM1, aL1)                              \
} while (0)

__global__ __launch_bounds__(512) void router_fused(
    const float* __restrict__ x, const unsigned short* __restrict__ Wp,
    const float* __restrict__ b, float* __restrict__ out)
{
    __shared__ unsigned short sB[KSP][2][192][BK];   // 96 KB -> 1 block/CU

    const int t  = threadIdx.x;
    const int w  = t >> 6;     // wave 0..7
    const int l  = t & 63;
    const int g  = w >> 1;     // k-split group 0..3
    const int h  = w & 1;      // token half 0/1
    const int lr = l & 15;     // A token-row / B expert-col
    const int lo = l >> 4;     // k-octet selector
    const int tokB = blockIdx.x * 64;
    const int tok0 = tokB + h * 32;
    const int kb   = g * KPER;

    const float* ax[2];
    ax[0] = x + (size_t)(tok0 + lr) * EMB + kb + lo * 8;
    ax[1] = ax[0] + (size_t)16 * EMB;

    // B staging: instr p=0..5 (q=6h+p): LDS rows 16q..16q+15 (16 x 64 B);
    // lane l -> row 16q+(l>>2), 16B piece l&3. Dest linear = lane map.
    const unsigned short* gb[6];
#pragma unroll
    for (int p = 0; p < 6; ++p)
        gb[p] = Wp + (size_t)(16 * (6 * h + p) + (l >> 2)) * EMB + kb + 8 * (l & 3);

    f32x4 accH[2][4], accL[2][4];
#pragma unroll
    for (int ti = 0; ti < 2; ++ti)
#pragma unroll
        for (int et = 0; et < 4; ++et) {
            accH[ti][et] = (f32x4){0.f, 0.f, 0.f, 0.f};
            accL[ti][et] = (f32x4){0.f, 0.f, 0.f, 0.f};
        }

    // prologue FIFO: A(0)(4), st(0)(6), A(1)(4) -> 14 outstanding
    float4 aA[2][2], aB[2][2];
#pragma unroll
    for (int ti = 0; ti < 2; ++ti) {
        aA[ti][0] = *reinterpret_cast<const float4*>(ax[ti]);
        aA[ti][1] = *reinterpret_cast<const float4*>(ax[ti] + 4);
    }
    __builtin_amdgcn_sched_barrier(0);
#pragma unroll
    for (int p = 0; p < 6; ++p)
        gl_lds16(gb[p], &sB[g][0][16 * (6 * h + p)][0]);
    __builtin_amdgcn_sched_barrier(0);
#pragma unroll
    for (int ti = 0; ti < 2; ++ti) {
        aB[ti][0] = *reinterpret_cast<const float4*>(ax[ti] + BK);
        aB[ti][1] = *reinterpret_cast<const float4*>(ax[ti] + BK + 4);
    }
    __builtin_amdgcn_sched_barrier(0);

#pragma unroll 1
    for (int kt = 0; kt < NCH - 2; kt += 2) {
        BODY(kt, aA, 0);
        BODY(kt + 1, aB, 1);
    }
    // peeled ks = NCH-2 (even -> aA, buf0): stage last chunk, no A-issue
    {
        asm volatile("s_waitcnt vmcnt(4)" ::: "memory");
        __builtin_amdgcn_s_barrier();
#pragma unroll
        for (int p = 0; p < 6; ++p)
            gl_lds16(gb[p] + (NCH - 1) * BK, &sB[g][1][16 * (6 * h + p)][0]);
        __builtin_amdgcn_sched_barrier(0);
        short8 aH0, aM0, aL0, aH1, aM1, aL1;
        build_frags(aA[0][0], aA[0][1], aH0, aM0, aL0);
        build_frags(aA[1][0], aA[1][1], aH1, aM1, aL1);
        MFMA_BLOCK(0, aH0, aM0, aL0, aH1, aM1, aL1)
    }
    // peeled ks = NCH-1 (odd -> aB, buf1): drain everything
    {
        asm volatile("s_waitcnt vmcnt(0)" ::: "memory");
        __builtin_amdgcn_s_barrier();
        short8 aH0, aM0, aL0, aH1, aM1, aL1;
        build_frags(aB[0][0], aB[0][1], aH0, aM0, aL0);
        build_frags(aB[1][0], aB[1][1], aH1, aM1, aL1);
        MFMA_BLOCK(1, aH0, aM0, aL0, aH1, aM1, aL1)
    }

    // ---- fused epilogue: in-block 4-split combine + top-2 + softmax ----
    __syncthreads();   // all sB reads done; drains outstanding counters
    float* logits = reinterpret_cast<float*>(&sB[0][0][0][0]); // [4][64][65]
#pragma unroll
    for (int ti = 0; ti < 2; ++ti)
#pragma unroll
        for (int et = 0; et < 4; ++et)
#pragma unroll
            for (int j = 0; j < 4; ++j) {
                const int ltok = h * 32 + ti * 16 + lo * 4 + j;
                logits[(g * 64 + ltok) * 65 + et * 16 + lr]
                    = accH[ti][et][j] + accL[ti][et][j];
            }
    __syncthreads();

    double* sv = reinterpret_cast<double*>(logits + KSP * 64 * 65); // [64][8][2]
    int*    si = reinterpret_cast<int*>(sv + 64 * 8 * 2);           // [64][8][2]

    const int tok  = t >> 3;    // 0..63
    const int part = t & 7;     // 8 experts each
    double v[8];
#pragma unroll
    for (int j = 0; j < 8; ++j) v[j] = 0.0;
#pragma unroll
    for (int gg = 0; gg < KSP; ++gg)
#pragma unroll
        for (int j = 0; j < 8; ++j)
            v[j] += (double)logits[(gg * 64 + tok) * 65 + part * 8 + j];
#pragma unroll
    for (int j = 0; j < 8; ++j) v[j] += (double)b[part * 8 + j];

    double v1 = -1e300, v2 = -1e300; int i1 = 0, i2 = 0;
#pragma unroll
    for (int j = 0; j < 8; ++j) {        // ascending: ties keep lowest idx
        const int e = part * 8 + j;
        if (v[j] > v1)      { v2 = v1; i2 = i1; v1 = v[j]; i1 = e; }
        else if (v[j] > v2) { v2 = v[j]; i2 = e; }
    }
    sv[(tok * 8 + part) * 2 + 0] = v1;
    sv[(tok * 8 + part) * 2 + 1] = v2;
    si[(tok * 8 + part) * 2 + 0] = i1;
    si[(tok * 8 + part) * 2 + 1] = i2;
    __syncthreads();

    if (part == 0) {
        double m1 = -1e300, m2 = -1e300; int j1 = 0, j2 = 0;
#pragma unroll
        for (int p = 0; p < 8; ++p)      // ascending parts: lowest idx on tie
#pragma unroll
            for (int r = 0; r < 2; ++r) {
                const double vv = sv[(tok * 8 + p) * 2 + r];
                const int    ii = si[(tok * 8 + p) * 2 + r];
                if (vv > m1)      { m2 = m1; j2 = j1; m1 = vv; j1 = ii; }
                else if (vv > m2) { m2 = vv; j2 = ii; }
            }
        const float e2  = expf((float)(m2 - m1));   // <= 1
        const float inv = 1.0f / (1.0f + e2);
        const int gt = tokB + tok;
        out[2 * gt]     = (float)j1;
        out[2 * gt + 1] = (float)j2;
        out[2 * TOKENS + 2 * gt]     = inv;
        out[2 * TOKENS + 2 * gt + 1] = e2 * inv;
    }
}

extern "C" void kernel_launch(void* const* d_in, const int* in_sizes, int n_in,
                              void* d_out, int out_size, void* d_ws, size_t ws_size,
                              hipStream_t stream) {
    const float* x = (const float*)d_in[0];
    const float* W = (const float*)d_in[1];
    const float* b = (const float*)d_in[2];
    float* out = (float*)d_out;
    unsigned short* Wp = (unsigned short*)d_ws;   // 1.5 MB, always fits

    split_w<<<dim3(NEXP * EMB / 1024), dim3(256), 0, stream>>>(W, Wp);
    router_fused<<<dim3(TOKENS / 64), dim3(512), 0, stream>>>(x, Wp, b, out);
}